// Round 1
// baseline (301.760 us; speedup 1.0000x reference)
//
#include <hip/hip_runtime.h>
#include <hip/hip_bf16.h>

#define DB 8
#define DT 2048
#define DC 1024
#define DH 128

typedef __attribute__((ext_vector_type(8))) short short8;
typedef __attribute__((ext_vector_type(4))) float f32x4;
typedef __attribute__((ext_vector_type(4))) int i32x4;
typedef __attribute__((ext_vector_type(4))) unsigned short u16x4;

// round-to-nearest-even f32 -> bf16 bits
static __device__ __forceinline__ unsigned short bfbits(float x){
    union { float f; unsigned u; } a; a.f = x;
    unsigned u = a.u;
    unsigned r = u + 0x7fffu + ((u >> 16) & 1u);
    return (unsigned short)(r >> 16);
}
static __device__ __forceinline__ unsigned pbf2(float lo, float hi){
    return (unsigned)bfbits(lo) | ((unsigned)bfbits(hi) << 16);
}

// WT[p][n][k] = W_p[k][n] (bf16), with softmax scale*log2e folded into Wq
__global__ __launch_bounds__(256) void prep_wt_kernel(const float* __restrict__ Wq,
                                                      const float* __restrict__ Wk,
                                                      const float* __restrict__ Wv,
                                                      unsigned short* __restrict__ WT){
    int gid = blockIdx.x * 256 + threadIdx.x;      // 0 .. 3*128*1024-1
    int p   = gid >> 17;
    int rem = gid & 131071;
    int n   = rem >> 10;
    int k   = rem & 1023;
    const float* W = (p == 0) ? Wq : (p == 1 ? Wk : Wv);
    float v = W[(size_t)k * DH + n];
    if (p == 0) v *= 0.08838834764831845f * 1.4426950408889634f;  // H^-0.5 * log2(e)
    WT[gid] = bfbits(v);
}

// Projection GEMM: out[m][n] = sum_k x[m][k] * W[k][n].
// grid (128, 3): blockIdx.x = M-tile (128 rows), blockIdx.y = projection.
// 4 waves, each 64x64 (4x4 fragments of 16x16), K-step 32, no LDS.
__global__ __launch_bounds__(256) void qkv_kernel(const float* __restrict__ x,
                                                  const unsigned short* __restrict__ WT,
                                                  unsigned short* __restrict__ Qb,
                                                  unsigned short* __restrict__ Kb,
                                                  unsigned short* __restrict__ VT){
    const int p    = blockIdx.y;
    const int m0   = blockIdx.x * 128;
    const int tid  = threadIdx.x;
    const int lane = tid & 63;
    const int wave = tid >> 6;
    const int g = lane >> 4, c = lane & 15;
    const int wr = wave >> 1, wc = wave & 1;
    const unsigned short* wt = WT + (size_t)p * (DH * DC);

    f32x4 acc[4][4] = {};

    for (int k0 = 0; k0 < DC; k0 += 32){
        short8 a[4], b[4];
#pragma unroll
        for (int mf = 0; mf < 4; ++mf){
            const float* xp = x + (size_t)(m0 + wr*64 + mf*16 + c) * DC + k0 + g*8;
            float4 v0 = *(const float4*)xp;
            float4 v1 = *(const float4*)(xp + 4);
            i32x4 t = { (int)pbf2(v0.x, v0.y), (int)pbf2(v0.z, v0.w),
                        (int)pbf2(v1.x, v1.y), (int)pbf2(v1.z, v1.w) };
            a[mf] = __builtin_bit_cast(short8, t);
        }
#pragma unroll
        for (int nf = 0; nf < 4; ++nf)
            b[nf] = *(const short8*)(wt + (size_t)(wc*64 + nf*16 + c) * DC + k0 + g*8);
#pragma unroll
        for (int mf = 0; mf < 4; ++mf)
#pragma unroll
            for (int nf = 0; nf < 4; ++nf)
                acc[mf][nf] = __builtin_amdgcn_mfma_f32_16x16x32_bf16(a[mf], b[nf], acc[mf][nf], 0, 0, 0);
    }

    if (p < 2){
        unsigned short* O = (p == 0) ? Qb : Kb;   // [B*T][H]
#pragma unroll
        for (int mf = 0; mf < 4; ++mf)
#pragma unroll
            for (int nf = 0; nf < 4; ++nf){
                int row = m0 + wr*64 + mf*16 + 4*g;
                int col = wc*64 + nf*16 + c;
#pragma unroll
                for (int r = 0; r < 4; ++r)
                    O[(size_t)(row + r) * DH + col] = bfbits(acc[mf][nf][r]);
            }
    } else {
        // V transposed per batch: VT[b][h][t]
        const int bb = m0 >> 11;
        const int tb = m0 & 2047;
#pragma unroll
        for (int mf = 0; mf < 4; ++mf)
#pragma unroll
            for (int nf = 0; nf < 4; ++nf){
                int t0  = tb + wr*64 + mf*16 + 4*g;
                int col = wc*64 + nf*16 + c;
                u16x4 v = { bfbits(acc[mf][nf][0]), bfbits(acc[mf][nf][1]),
                            bfbits(acc[mf][nf][2]), bfbits(acc[mf][nf][3]) };
                *(u16x4*)(VT + ((size_t)bb * DH + col) * DT + t0) = v;
            }
    }
}

// Causal flash attention. 1 wave per block, 16 q-rows, kv-tile = 32.
// Swapped QK^T: S^T = mfma(K, Q) so q = lane&15 is lane-local.
// O^T = mfma(V^T, P^T) accumulated over kv tiles; scores already in exp2 domain.
__global__ __launch_bounds__(64) void attn_kernel(const unsigned short* __restrict__ Qb,
                                                  const unsigned short* __restrict__ Kb,
                                                  const unsigned short* __restrict__ VT,
                                                  float* __restrict__ out){
    const int lane = threadIdx.x;
    const int g = lane >> 4, c = lane & 15;
    const int bi = blockIdx.x;
    const int b = bi >> 7, qt = bi & 127;
    const int q0 = qt * 16;
    const int q  = q0 + c;

    short8 qf[4];
#pragma unroll
    for (int hc = 0; hc < 4; ++hc)
        qf[hc] = *(const short8*)(Qb + ((size_t)b*DT + q0 + c) * DH + hc*32 + g*8);

    f32x4 acc[8] = {};
    float m = -1e30f, l = 0.f;
    const int ntiles = (q0 + 16 + 31) >> 5;

    for (int kt = 0; kt < ntiles; ++kt){
        const int kv0 = kt * 32;
        f32x4 s0 = {0.f,0.f,0.f,0.f}, s1 = {0.f,0.f,0.f,0.f};
#pragma unroll
        for (int hc = 0; hc < 4; ++hc){
            short8 kf0 = *(const short8*)(Kb + ((size_t)b*DT + kv0 +      c) * DH + hc*32 + g*8);
            short8 kf1 = *(const short8*)(Kb + ((size_t)b*DT + kv0 + 16 + c) * DH + hc*32 + g*8);
            s0 = __builtin_amdgcn_mfma_f32_16x16x32_bf16(kf0, qf[hc], s0, 0,0,0);
            s1 = __builtin_amdgcn_mfma_f32_16x16x32_bf16(kf1, qf[hc], s1, 0,0,0);
        }
        if (kv0 + 31 > q0){
#pragma unroll
            for (int r = 0; r < 4; ++r){
                if (kv0 +      4*g + r > q) s0[r] = -1e30f;
                if (kv0 + 16 + 4*g + r > q) s1[r] = -1e30f;
            }
        }
        float tm = fmaxf(fmaxf(fmaxf(s0[0], s0[1]), fmaxf(s0[2], s0[3])),
                         fmaxf(fmaxf(s1[0], s1[1]), fmaxf(s1[2], s1[3])));
        tm = fmaxf(tm, __shfl_xor(tm, 16));
        tm = fmaxf(tm, __shfl_xor(tm, 32));
        const float mn = fmaxf(m, tm);
        const float rs = exp2f(m - mn);
        float p0[4], p1[4]; float ps = 0.f;
#pragma unroll
        for (int r = 0; r < 4; ++r){
            p0[r] = exp2f(s0[r] - mn);
            p1[r] = exp2f(s1[r] - mn);
            ps += p0[r] + p1[r];
        }
        ps += __shfl_xor(ps, 16);
        ps += __shfl_xor(ps, 32);
        l = l * rs + ps; m = mn;
#pragma unroll
        for (int mt = 0; mt < 8; ++mt) acc[mt] *= rs;

        // Redistribute P (S^T D-layout) into PV B-fragment layout (kv = 8g+i).
        const unsigned pk0 = pbf2(p0[0], p0[1]), pk1 = pbf2(p0[2], p0[3]);
        const unsigned pk2 = pbf2(p1[0], p1[1]), pk3 = pbf2(p1[2], p1[3]);
        const int src0 = c + (((2*g    ) & 3) << 4);
        const int src1 = c + (((2*g + 1) & 3) << 4);
        const int sel  = g >> 1;
        unsigned a0 = __shfl(pk0, src0), a2 = __shfl(pk2, src0);
        unsigned b0 = __shfl(pk1, src0), b2 = __shfl(pk3, src0);
        unsigned c0 = __shfl(pk0, src1), c2 = __shfl(pk2, src1);
        unsigned d0 = __shfl(pk1, src1), d2 = __shfl(pk3, src1);
        i32x4 pw = { (int)(sel ? a2 : a0), (int)(sel ? b2 : b0),
                     (int)(sel ? c2 : c0), (int)(sel ? d2 : d0) };
        short8 pf = __builtin_bit_cast(short8, pw);
#pragma unroll
        for (int mt = 0; mt < 8; ++mt){
            short8 vf = *(const short8*)(VT + ((size_t)b*DH + mt*16 + c) * DT + kv0 + g*8);
            acc[mt] = __builtin_amdgcn_mfma_f32_16x16x32_bf16(vf, pf, acc[mt], 0,0,0);
        }
    }

    const float inv = 1.0f / l;
    float* orow = out + ((size_t)b*DT + q) * DH;
#pragma unroll
    for (int mt = 0; mt < 8; ++mt){
        f32x4 v = acc[mt] * inv;
        *(f32x4*)(orow + mt*16 + 4*g) = v;
    }
}

extern "C" void kernel_launch(void* const* d_in, const int* in_sizes, int n_in,
                              void* d_out, int out_size, void* d_ws, size_t ws_size,
                              hipStream_t stream){
    const float* x  = (const float*)d_in[0];
    const float* Wq = (const float*)d_in[1];
    const float* Wk = (const float*)d_in[2];
    const float* Wv = (const float*)d_in[3];
    float* out = (float*)d_out;

    unsigned short* WT = (unsigned short*)d_ws;          // 3*128*1024 bf16
    unsigned short* Qb = WT + 3 * DH * DC;               // [B*T][H]
    unsigned short* Kb = Qb + (size_t)DB * DT * DH;      // [B*T][H]
    unsigned short* VT = Kb + (size_t)DB * DT * DH;      // [B][H][T]

    hipLaunchKernelGGL(prep_wt_kernel, dim3(1536), dim3(256), 0, stream, Wq, Wk, Wv, WT);
    hipLaunchKernelGGL(qkv_kernel, dim3(128, 3), dim3(256), 0, stream, x, WT, Qb, Kb, VT);
    hipLaunchKernelGGL(attn_kernel, dim3(DB * (DT / 16)), dim3(64), 0, stream, Qb, Kb, VT, out);
}

// Round 2
// 200.742 us; speedup vs baseline: 1.5032x; 1.5032x over previous
//
#include <hip/hip_runtime.h>
#include <hip/hip_bf16.h>

#define DB 8
#define DT 2048
#define DC 1024
#define DH 128

typedef __attribute__((ext_vector_type(8))) short short8;
typedef __attribute__((ext_vector_type(4))) float f32x4;
typedef __attribute__((ext_vector_type(4))) int i32x4;
typedef __attribute__((ext_vector_type(4))) unsigned short u16x4;

// round-to-nearest-even f32 -> bf16 bits
static __device__ __forceinline__ unsigned short bfbits(float x){
    union { float f; unsigned u; } a; a.f = x;
    unsigned u = a.u;
    unsigned r = u + 0x7fffu + ((u >> 16) & 1u);
    return (unsigned short)(r >> 16);
}
static __device__ __forceinline__ unsigned pbf2(float lo, float hi){
    return (unsigned)bfbits(lo) | ((unsigned)bfbits(hi) << 16);
}

// WT[p][n][k] = W_p[k][n] (bf16) == flat [384][1024]; scale*log2e folded into Wq
__global__ __launch_bounds__(256) void prep_wt_kernel(const float* __restrict__ Wq,
                                                      const float* __restrict__ Wk,
                                                      const float* __restrict__ Wv,
                                                      unsigned short* __restrict__ WT){
    int gid = blockIdx.x * 256 + threadIdx.x;      // 0 .. 3*128*1024-1
    int p   = gid >> 17;
    int rem = gid & 131071;
    int n   = rem >> 10;
    int k   = rem & 1023;
    const float* W = (p == 0) ? Wq : (p == 1 ? Wk : Wv);
    float v = W[(size_t)k * DH + n];
    if (p == 0) v *= 0.08838834764831845f * 1.4426950408889634f;  // H^-0.5 * log2(e)
    WT[gid] = bfbits(v);
}

// Fused QKV projection: x read ONCE. BM=32 rows/block, 512 blocks, 4 waves.
// Wave w covers cols n0 = w*96 .. +95 of the 384 fused output cols.
__global__ __launch_bounds__(256) void qkv_kernel(const float* __restrict__ x,
                                                  const unsigned short* __restrict__ WT,
                                                  unsigned short* __restrict__ Qb,
                                                  unsigned short* __restrict__ Kb,
                                                  unsigned short* __restrict__ VT){
    const int m0   = blockIdx.x * 32;
    const int lane = threadIdx.x & 63;
    const int w    = threadIdx.x >> 6;
    const int g = lane >> 4, c = lane & 15;
    const int n0 = w * 96;

    f32x4 acc[2][6] = {};

    for (int k0 = 0; k0 < DC; k0 += 32){
        short8 a[2], bf[6];
#pragma unroll
        for (int mf = 0; mf < 2; ++mf){
            const float* xp = x + (size_t)(m0 + mf*16 + c) * DC + k0 + g*8;
            float4 v0 = *(const float4*)xp;
            float4 v1 = *(const float4*)(xp + 4);
            i32x4 t = { (int)pbf2(v0.x, v0.y), (int)pbf2(v0.z, v0.w),
                        (int)pbf2(v1.x, v1.y), (int)pbf2(v1.z, v1.w) };
            a[mf] = __builtin_bit_cast(short8, t);
        }
#pragma unroll
        for (int nf = 0; nf < 6; ++nf)
            bf[nf] = *(const short8*)(WT + (size_t)(n0 + nf*16 + c) * DC + k0 + g*8);
#pragma unroll
        for (int mf = 0; mf < 2; ++mf)
#pragma unroll
            for (int nf = 0; nf < 6; ++nf)
                acc[mf][nf] = __builtin_amdgcn_mfma_f32_16x16x32_bf16(a[mf], bf[nf], acc[mf][nf], 0, 0, 0);
    }

    const int bb = m0 >> 11;         // batch (32-row tiles never cross batch)
    const int tb = m0 & 2047;
#pragma unroll
    for (int mf = 0; mf < 2; ++mf)
#pragma unroll
        for (int nf = 0; nf < 6; ++nf){
            const int n  = n0 + nf*16;         // fused col base (16-aligned, single p)
            const int p  = n >> 7;
            const int np = (n & 127) + c;
            const int row = m0 + mf*16 + 4*g;  // global m
            if (p < 2){
                unsigned short* O = (p == 0) ? Qb : Kb;   // [B*T][H]
#pragma unroll
                for (int r = 0; r < 4; ++r)
                    O[(size_t)(row + r) * DH + np] = bfbits(acc[mf][nf][r]);
            } else {
                const int t0 = tb + mf*16 + 4*g;
                u16x4 v = { bfbits(acc[mf][nf][0]), bfbits(acc[mf][nf][1]),
                            bfbits(acc[mf][nf][2]), bfbits(acc[mf][nf][3]) };
                *(u16x4*)(VT + ((size_t)bb * DH + np) * DT + t0) = v;
            }
        }
}

// Causal flash attention. 4 waves/block cooperating on one 16-row q-tile:
// wave w handles kv-tiles w, w+4, w+8, ... with private online-softmax state,
// then the partials are merged through LDS (max-of-maxes rescale).
__global__ __launch_bounds__(256) void attn_kernel(const unsigned short* __restrict__ Qb,
                                                   const unsigned short* __restrict__ Kb,
                                                   const unsigned short* __restrict__ VT,
                                                   float* __restrict__ out){
    __shared__ float facc[4 * 16 * 132];
    __shared__ float sm[64];
    __shared__ float sl[64];

    const int tid  = threadIdx.x;
    const int lane = tid & 63;
    const int w    = tid >> 6;
    const int g = lane >> 4, c = lane & 15;
    const int bi = blockIdx.x;
    const int b = bi >> 7, qt = bi & 127;
    const int q0 = qt * 16;
    const int q  = q0 + c;

    short8 qf[4];
#pragma unroll
    for (int hc = 0; hc < 4; ++hc)
        qf[hc] = *(const short8*)(Qb + ((size_t)b*DT + q0 + c) * DH + hc*32 + g*8);

    f32x4 acc[8] = {};
    float m = -1e30f, l = 0.f;
    const int ntiles = (q0 + 16 + 31) >> 5;

    for (int kt = w; kt < ntiles; kt += 4){
        const int kv0 = kt * 32;
        f32x4 s0 = {0.f,0.f,0.f,0.f}, s1 = {0.f,0.f,0.f,0.f};
#pragma unroll
        for (int hc = 0; hc < 4; ++hc){
            short8 kf0 = *(const short8*)(Kb + ((size_t)b*DT + kv0 +      c) * DH + hc*32 + g*8);
            short8 kf1 = *(const short8*)(Kb + ((size_t)b*DT + kv0 + 16 + c) * DH + hc*32 + g*8);
            s0 = __builtin_amdgcn_mfma_f32_16x16x32_bf16(kf0, qf[hc], s0, 0,0,0);
            s1 = __builtin_amdgcn_mfma_f32_16x16x32_bf16(kf1, qf[hc], s1, 0,0,0);
        }
        if (kv0 + 31 > q0){
#pragma unroll
            for (int r = 0; r < 4; ++r){
                if (kv0 +      4*g + r > q) s0[r] = -1e30f;
                if (kv0 + 16 + 4*g + r > q) s1[r] = -1e30f;
            }
        }
        float tm = fmaxf(fmaxf(fmaxf(s0[0], s0[1]), fmaxf(s0[2], s0[3])),
                         fmaxf(fmaxf(s1[0], s1[1]), fmaxf(s1[2], s1[3])));
        tm = fmaxf(tm, __shfl_xor(tm, 16));
        tm = fmaxf(tm, __shfl_xor(tm, 32));
        const float mn = fmaxf(m, tm);
        const float rs = exp2f(m - mn);
        float p0[4], p1[4]; float ps = 0.f;
#pragma unroll
        for (int r = 0; r < 4; ++r){
            p0[r] = exp2f(s0[r] - mn);
            p1[r] = exp2f(s1[r] - mn);
            ps += p0[r] + p1[r];
        }
        ps += __shfl_xor(ps, 16);
        ps += __shfl_xor(ps, 32);
        l = l * rs + ps; m = mn;
#pragma unroll
        for (int mt = 0; mt < 8; ++mt) acc[mt] *= rs;

        // Redistribute P (S^T D-layout) into PV B-fragment layout (kv = 8g+i).
        const unsigned pk0 = pbf2(p0[0], p0[1]), pk1 = pbf2(p0[2], p0[3]);
        const unsigned pk2 = pbf2(p1[0], p1[1]), pk3 = pbf2(p1[2], p1[3]);
        const int src0 = c + (((2*g    ) & 3) << 4);
        const int src1 = c + (((2*g + 1) & 3) << 4);
        const int sel  = g >> 1;
        unsigned a0 = __shfl(pk0, src0), a2 = __shfl(pk2, src0);
        unsigned b0 = __shfl(pk1, src0), b2 = __shfl(pk3, src0);
        unsigned c0 = __shfl(pk0, src1), c2 = __shfl(pk2, src1);
        unsigned d0 = __shfl(pk1, src1), d2 = __shfl(pk3, src1);
        i32x4 pw = { (int)(sel ? a2 : a0), (int)(sel ? b2 : b0),
                     (int)(sel ? c2 : c0), (int)(sel ? d2 : d0) };
        short8 pf = __builtin_bit_cast(short8, pw);
#pragma unroll
        for (int mt = 0; mt < 8; ++mt){
            short8 vf = *(const short8*)(VT + ((size_t)b*DH + mt*16 + c) * DT + kv0 + g*8);
            acc[mt] = __builtin_amdgcn_mfma_f32_16x16x32_bf16(vf, pf, acc[mt], 0,0,0);
        }
    }

    // ---- merge the 4 per-wave partials ----
    if (g == 0) sm[w*16 + c] = m;
    __syncthreads();
    const float M = fmaxf(fmaxf(sm[c], sm[16 + c]), fmaxf(sm[32 + c], sm[48 + c]));
    const float scale = exp2f(m - M);          // 0 for idle waves (m = -1e30)
    if (g == 0) sl[w*16 + c] = l * scale;
#pragma unroll
    for (int mt = 0; mt < 8; ++mt){
        f32x4 v = acc[mt] * scale;
        *(f32x4*)&facc[(w*16 + c) * 132 + mt*16 + 4*g] = v;
    }
    __syncthreads();
    const float L = sl[c] + sl[16 + c] + sl[32 + c] + sl[48 + c];
    const float inv = 1.0f / L;
    float* orow = out + ((size_t)b*DT + q0 + c) * DH;
#pragma unroll
    for (int j = 0; j < 2; ++j){
        const int h0 = w*32 + g*8 + j*4;
        f32x4 s = {0.f,0.f,0.f,0.f};
#pragma unroll
        for (int w2 = 0; w2 < 4; ++w2)
            s += *(const f32x4*)&facc[(w2*16 + c) * 132 + h0];
        s *= inv;
        *(f32x4*)(orow + h0) = s;
    }
}

extern "C" void kernel_launch(void* const* d_in, const int* in_sizes, int n_in,
                              void* d_out, int out_size, void* d_ws, size_t ws_size,
                              hipStream_t stream){
    const float* x  = (const float*)d_in[0];
    const float* Wq = (const float*)d_in[1];
    const float* Wk = (const float*)d_in[2];
    const float* Wv = (const float*)d_in[3];
    float* out = (float*)d_out;

    unsigned short* WT = (unsigned short*)d_ws;          // [384][1024] bf16
    unsigned short* Qb = WT + 3 * DH * DC;               // [B*T][H]
    unsigned short* Kb = Qb + (size_t)DB * DT * DH;      // [B*T][H]
    unsigned short* VT = Kb + (size_t)DB * DT * DH;      // [B][H][T]

    hipLaunchKernelGGL(prep_wt_kernel, dim3(1536), dim3(256), 0, stream, Wq, Wk, Wv, WT);
    hipLaunchKernelGGL(qkv_kernel, dim3(512), dim3(256), 0, stream, x, WT, Qb, Kb, VT);
    hipLaunchKernelGGL(attn_kernel, dim3(DB * (DT / 16)), dim3(256), 0, stream, Qb, Kb, VT, out);
}

// Round 3
// 160.439 us; speedup vs baseline: 1.8808x; 1.2512x over previous
//
#include <hip/hip_runtime.h>
#include <hip/hip_bf16.h>

#define DB 8
#define DT 2048
#define DC 1024
#define DH 128

typedef __attribute__((ext_vector_type(8))) short short8;
typedef __attribute__((ext_vector_type(4))) float f32x4;
typedef __attribute__((ext_vector_type(4))) int i32x4;
typedef __attribute__((ext_vector_type(4))) unsigned short u16x4;

// round-to-nearest-even f32 -> bf16 bits
static __device__ __forceinline__ unsigned short bfbits(float x){
    union { float f; unsigned u; } a; a.f = x;
    unsigned u = a.u;
    unsigned r = u + 0x7fffu + ((u >> 16) & 1u);
    return (unsigned short)(r >> 16);
}
static __device__ __forceinline__ unsigned pbf2(float lo, float hi){
    return (unsigned)bfbits(lo) | ((unsigned)bfbits(hi) << 16);
}

// WT[p][n][k] = W_p[k][n] (bf16) == flat [384][1024]; scale*log2e folded into Wq
__global__ __launch_bounds__(256) void prep_wt_kernel(const float* __restrict__ Wq,
                                                      const float* __restrict__ Wk,
                                                      const float* __restrict__ Wv,
                                                      unsigned short* __restrict__ WT){
    int gid = blockIdx.x * 256 + threadIdx.x;      // 0 .. 3*128*1024-1
    int p   = gid >> 17;
    int rem = gid & 131071;
    int n   = rem >> 10;
    int k   = rem & 1023;
    const float* W = (p == 0) ? Wq : (p == 1 ? Wk : Wv);
    float v = W[(size_t)k * DH + n];
    if (p == 0) v *= 0.08838834764831845f * 1.4426950408889634f;  // H^-0.5 * log2(e)
    WT[gid] = bfbits(v);
}

// Fused QKV projection: x read ONCE. BM=32 rows/block, 512 blocks, 4 waves.
// Wave w covers cols n0 = w*96 .. +95 of the 384 fused output cols.
__global__ __launch_bounds__(256, 2) void qkv_kernel(const float* __restrict__ x,
                                                     const unsigned short* __restrict__ WT,
                                                     unsigned short* __restrict__ Qb,
                                                     unsigned short* __restrict__ Kb,
                                                     unsigned short* __restrict__ VT){
    const int m0   = blockIdx.x * 32;
    const int lane = threadIdx.x & 63;
    const int w    = threadIdx.x >> 6;
    const int g = lane >> 4, c = lane & 15;
    const int n0 = w * 96;

    f32x4 acc[2][6] = {};

    for (int k0 = 0; k0 < DC; k0 += 32){
        short8 a[2], bf[6];
#pragma unroll
        for (int mf = 0; mf < 2; ++mf){
            const float* xp = x + (size_t)(m0 + mf*16 + c) * DC + k0 + g*8;
            float4 v0 = *(const float4*)xp;
            float4 v1 = *(const float4*)(xp + 4);
            i32x4 t = { (int)pbf2(v0.x, v0.y), (int)pbf2(v0.z, v0.w),
                        (int)pbf2(v1.x, v1.y), (int)pbf2(v1.z, v1.w) };
            a[mf] = __builtin_bit_cast(short8, t);
        }
#pragma unroll
        for (int nf = 0; nf < 6; ++nf)
            bf[nf] = *(const short8*)(WT + (size_t)(n0 + nf*16 + c) * DC + k0 + g*8);
#pragma unroll
        for (int mf = 0; mf < 2; ++mf)
#pragma unroll
            for (int nf = 0; nf < 6; ++nf)
                acc[mf][nf] = __builtin_amdgcn_mfma_f32_16x16x32_bf16(a[mf], bf[nf], acc[mf][nf], 0, 0, 0);
    }

    const int bb = m0 >> 11;         // batch (32-row tiles never cross batch)
    const int tb = m0 & 2047;
#pragma unroll
    for (int mf = 0; mf < 2; ++mf)
#pragma unroll
        for (int nf = 0; nf < 6; ++nf){
            const int n  = n0 + nf*16;         // fused col base (16-aligned, single p)
            const int p  = n >> 7;
            const int np = (n & 127) + c;
            const int row = m0 + mf*16 + 4*g;  // global m
            if (p < 2){
                unsigned short* O = (p == 0) ? Qb : Kb;   // [B*T][H]
#pragma unroll
                for (int r = 0; r < 4; ++r)
                    O[(size_t)(row + r) * DH + np] = bfbits(acc[mf][nf][r]);
            } else {
                const int t0 = tb + mf*16 + 4*g;
                u16x4 v = { bfbits(acc[mf][nf][0]), bfbits(acc[mf][nf][1]),
                            bfbits(acc[mf][nf][2]), bfbits(acc[mf][nf][3]) };
                *(u16x4*)(VT + ((size_t)bb * DH + np) * DT + t0) = v;
            }
        }
}

// Causal flash attention. 4 waves/block cooperating on one 16-row q-tile:
// wave w handles kv-tiles w, w+4, ... with private online-softmax state,
// then partials merge through LDS in two h-halves (17.5 KB LDS).
__global__ __launch_bounds__(256, 2) void attn_kernel(const unsigned short* __restrict__ Qb,
                                                      const unsigned short* __restrict__ Kb,
                                                      const unsigned short* __restrict__ VT,
                                                      float* __restrict__ out){
    __shared__ float facc[4 * 16 * 68];
    __shared__ float sm[64];
    __shared__ float sl[64];

    const int tid  = threadIdx.x;
    const int lane = tid & 63;
    const int w    = tid >> 6;
    const int g = lane >> 4, c = lane & 15;
    const int bi = blockIdx.x;
    // largest causal tiles first: bi 0..7 -> qt=127 (all batches), etc.
    const int b  = bi & 7;
    const int qt = 127 - (bi >> 3);
    const int q0 = qt * 16;
    const int q  = q0 + c;

    short8 qf[4];
#pragma unroll
    for (int hc = 0; hc < 4; ++hc)
        qf[hc] = *(const short8*)(Qb + ((size_t)b*DT + q0 + c) * DH + hc*32 + g*8);

    f32x4 acc[8] = {};
    float m = -1e30f, l = 0.f;
    const int ntiles = (q0 + 16 + 31) >> 5;

    for (int kt = w; kt < ntiles; kt += 4){
        const int kv0 = kt * 32;
        f32x4 s0 = {0.f,0.f,0.f,0.f}, s1 = {0.f,0.f,0.f,0.f};
#pragma unroll
        for (int hc = 0; hc < 4; ++hc){
            short8 kf0 = *(const short8*)(Kb + ((size_t)b*DT + kv0 +      c) * DH + hc*32 + g*8);
            short8 kf1 = *(const short8*)(Kb + ((size_t)b*DT + kv0 + 16 + c) * DH + hc*32 + g*8);
            s0 = __builtin_amdgcn_mfma_f32_16x16x32_bf16(kf0, qf[hc], s0, 0,0,0);
            s1 = __builtin_amdgcn_mfma_f32_16x16x32_bf16(kf1, qf[hc], s1, 0,0,0);
        }
        if (kv0 + 31 > q0){
#pragma unroll
            for (int r = 0; r < 4; ++r){
                if (kv0 +      4*g + r > q) s0[r] = -1e30f;
                if (kv0 + 16 + 4*g + r > q) s1[r] = -1e30f;
            }
        }
        float tm = fmaxf(fmaxf(fmaxf(s0[0], s0[1]), fmaxf(s0[2], s0[3])),
                         fmaxf(fmaxf(s1[0], s1[1]), fmaxf(s1[2], s1[3])));
        tm = fmaxf(tm, __shfl_xor(tm, 16));
        tm = fmaxf(tm, __shfl_xor(tm, 32));
        const float mn = fmaxf(m, tm);
        const float rs = exp2f(m - mn);
        float p0[4], p1[4]; float ps = 0.f;
#pragma unroll
        for (int r = 0; r < 4; ++r){
            p0[r] = exp2f(s0[r] - mn);
            p1[r] = exp2f(s1[r] - mn);
            ps += p0[r] + p1[r];
        }
        ps += __shfl_xor(ps, 16);
        ps += __shfl_xor(ps, 32);
        l = l * rs + ps; m = mn;
#pragma unroll
        for (int mt = 0; mt < 8; ++mt) acc[mt] *= rs;

        // Redistribute P (S^T D-layout) into PV B-fragment layout (kv = 8g+i).
        const unsigned pk0 = pbf2(p0[0], p0[1]), pk1 = pbf2(p0[2], p0[3]);
        const unsigned pk2 = pbf2(p1[0], p1[1]), pk3 = pbf2(p1[2], p1[3]);
        const int src0 = c + (((2*g    ) & 3) << 4);
        const int src1 = c + (((2*g + 1) & 3) << 4);
        const int sel  = g >> 1;
        unsigned a0 = __shfl(pk0, src0), a2 = __shfl(pk2, src0);
        unsigned b0 = __shfl(pk1, src0), b2 = __shfl(pk3, src0);
        unsigned c0 = __shfl(pk0, src1), c2 = __shfl(pk2, src1);
        unsigned d0 = __shfl(pk1, src1), d2 = __shfl(pk3, src1);
        i32x4 pw = { (int)(sel ? a2 : a0), (int)(sel ? b2 : b0),
                     (int)(sel ? c2 : c0), (int)(sel ? d2 : d0) };
        short8 pf = __builtin_bit_cast(short8, pw);
#pragma unroll
        for (int mt = 0; mt < 8; ++mt){
            short8 vf = *(const short8*)(VT + ((size_t)b*DH + mt*16 + c) * DT + kv0 + g*8);
            acc[mt] = __builtin_amdgcn_mfma_f32_16x16x32_bf16(vf, pf, acc[mt], 0,0,0);
        }
    }

    // ---- merge the 4 per-wave partials (two h-halves to halve LDS) ----
    if (g == 0) sm[w*16 + c] = m;
    __syncthreads();
    const float M = fmaxf(fmaxf(sm[c], sm[16 + c]), fmaxf(sm[32 + c], sm[48 + c]));
    const float scale = exp2f(m - M);          // 0 for idle waves (m = -1e30)
    if (g == 0) sl[w*16 + c] = l * scale;

    float inv = 0.f;
    float* orow = out + ((size_t)b*DT + q0 + c) * DH;
#pragma unroll
    for (int ph = 0; ph < 2; ++ph){
#pragma unroll
        for (int mt = 0; mt < 4; ++mt){
            f32x4 v = acc[ph*4 + mt] * scale;
            *(f32x4*)&facc[(w*16 + c) * 68 + mt*16 + 4*g] = v;
        }
        __syncthreads();
        if (ph == 0){
            const float L = sl[c] + sl[16 + c] + sl[32 + c] + sl[48 + c];
            inv = 1.0f / L;
        }
        const int ho = w*16 + g*4;             // 0..60, col within this half
        f32x4 s = {0.f,0.f,0.f,0.f};
#pragma unroll
        for (int w2 = 0; w2 < 4; ++w2)
            s += *(const f32x4*)&facc[(w2*16 + c) * 68 + ho];
        s *= inv;
        *(f32x4*)(orow + ph*64 + ho) = s;
        if (ph == 0) __syncthreads();
    }
}

extern "C" void kernel_launch(void* const* d_in, const int* in_sizes, int n_in,
                              void* d_out, int out_size, void* d_ws, size_t ws_size,
                              hipStream_t stream){
    const float* x  = (const float*)d_in[0];
    const float* Wq = (const float*)d_in[1];
    const float* Wk = (const float*)d_in[2];
    const float* Wv = (const float*)d_in[3];
    float* out = (float*)d_out;

    unsigned short* WT = (unsigned short*)d_ws;          // [384][1024] bf16
    unsigned short* Qb = WT + 3 * DH * DC;               // [B*T][H]
    unsigned short* Kb = Qb + (size_t)DB * DT * DH;      // [B*T][H]
    unsigned short* VT = Kb + (size_t)DB * DT * DH;      // [B][H][T]

    hipLaunchKernelGGL(prep_wt_kernel, dim3(1536), dim3(256), 0, stream, Wq, Wk, Wv, WT);
    hipLaunchKernelGGL(qkv_kernel, dim3(512), dim3(256), 0, stream, x, WT, Qb, Kb, VT);
    hipLaunchKernelGGL(attn_kernel, dim3(DB * (DT / 16)), dim3(256), 0, stream, Qb, Kb, VT, out);
}

// Round 4
// 139.130 us; speedup vs baseline: 2.1689x; 1.1532x over previous
//
#include <hip/hip_runtime.h>
#include <hip/hip_bf16.h>

#define DB 8
#define DT 2048
#define DC 1024
#define DH 128

typedef __attribute__((ext_vector_type(8))) short short8;
typedef __attribute__((ext_vector_type(4))) float f32x4;
typedef __attribute__((ext_vector_type(4))) int i32x4;
typedef __attribute__((ext_vector_type(4))) unsigned short u16x4;

// round-to-nearest-even f32 -> bf16 bits
static __device__ __forceinline__ unsigned short bfbits(float x){
    union { float f; unsigned u; } a; a.f = x;
    unsigned u = a.u;
    unsigned r = u + 0x7fffu + ((u >> 16) & 1u);
    return (unsigned short)(r >> 16);
}
static __device__ __forceinline__ unsigned pbf2(float lo, float hi){
    return (unsigned)bfbits(lo) | ((unsigned)bfbits(hi) << 16);
}

// WT[p][n][k] = W_p[k][n] (bf16) == flat [384][1024]; scale*log2e folded into Wq
__global__ __launch_bounds__(256) void prep_wt_kernel(const float* __restrict__ Wq,
                                                      const float* __restrict__ Wk,
                                                      const float* __restrict__ Wv,
                                                      unsigned short* __restrict__ WT){
    int gid = blockIdx.x * 256 + threadIdx.x;      // 0 .. 3*128*1024-1
    int p   = gid >> 17;
    int rem = gid & 131071;
    int n   = rem >> 10;
    int k   = rem & 1023;
    const float* W = (p == 0) ? Wq : (p == 1 ? Wk : Wv);
    float v = W[(size_t)k * DH + n];
    if (p == 0) v *= 0.08838834764831845f * 1.4426950408889634f;  // H^-0.5 * log2(e)
    WT[gid] = bfbits(v);
}

// Fused QKV projection, LDS-staged.
// BM=32 rows/block, 512 blocks, 8 waves x 48 cols. BK=64, double-buffered
// x-tile staged reg->LDS as bf16 with padded stride 72 (bank-conflict-free
// b128 reads). WT B-frags direct from L2. x read once from HBM.
#define QBK 64
#define QLDW 72
__global__ __launch_bounds__(512, 4) void qkv_kernel(const float* __restrict__ x,
                                                     const unsigned short* __restrict__ WT,
                                                     unsigned short* __restrict__ Qb,
                                                     unsigned short* __restrict__ Kb,
                                                     unsigned short* __restrict__ VT){
    __shared__ unsigned short xs[2 * 32 * QLDW];

    const int tid  = threadIdx.x;
    const int lane = tid & 63;
    const int w    = tid >> 6;            // 0..7
    const int g = lane >> 4, c = lane & 15;
    const int m0 = blockIdx.x * 32;
    const int n0 = w * 48;

    // staging map: thread -> 16B (4 f32) of the 32x64 tile
    const int sr = tid >> 4;              // row 0..31
    const int sc = (tid & 15) * 4;        // f32 col 0..60
    const float* xg = x + (size_t)(m0 + sr) * DC + sc;
    unsigned short* xw = xs + sr * QLDW + sc;

    f32x4 acc[2][3] = {};

    // prologue: stage tile 0
    {
        float4 v = *(const float4*)xg;
        u16x4 h = { bfbits(v.x), bfbits(v.y), bfbits(v.z), bfbits(v.w) };
        *(u16x4*)xw = h;
    }

    for (int t = 0; t < DC / QBK; ++t){
        const int cur = t & 1;
        __syncthreads();                       // staged buf[cur] visible
        float4 nv;
        if (t < DC / QBK - 1)
            nv = *(const float4*)(xg + (t + 1) * QBK);   // issue early (T14)
        const unsigned short* xr = xs + cur * (32 * QLDW);
#pragma unroll
        for (int kk = 0; kk < 2; ++kk){
            short8 bfr[3], af[2];
#pragma unroll
            for (int nf = 0; nf < 3; ++nf)
                bfr[nf] = *(const short8*)(WT + (size_t)(n0 + nf*16 + c) * DC + t*QBK + kk*32 + g*8);
#pragma unroll
            for (int mf = 0; mf < 2; ++mf)
                af[mf] = *(const short8*)(xr + (mf*16 + c) * QLDW + kk*32 + g*8);
#pragma unroll
            for (int mf = 0; mf < 2; ++mf)
#pragma unroll
                for (int nf = 0; nf < 3; ++nf)
                    acc[mf][nf] = __builtin_amdgcn_mfma_f32_16x16x32_bf16(af[mf], bfr[nf], acc[mf][nf], 0, 0, 0);
        }
        if (t < DC / QBK - 1){
            u16x4 h = { bfbits(nv.x), bfbits(nv.y), bfbits(nv.z), bfbits(nv.w) };
            *(u16x4*)(xw + (1 - cur) * (32 * QLDW)) = h;   // write late
        }
    }

    const int bb = m0 >> 11;         // batch (32-row tiles never cross batch)
    const int tb = m0 & 2047;
#pragma unroll
    for (int mf = 0; mf < 2; ++mf)
#pragma unroll
        for (int nf = 0; nf < 3; ++nf){
            const int n  = n0 + nf*16;         // fused col base (16-aligned, single p)
            const int p  = n >> 7;
            const int np = (n & 127) + c;
            const int row = m0 + mf*16 + 4*g;  // global m
            if (p < 2){
                unsigned short* O = (p == 0) ? Qb : Kb;   // [B*T][H]
#pragma unroll
                for (int r = 0; r < 4; ++r)
                    O[(size_t)(row + r) * DH + np] = bfbits(acc[mf][nf][r]);
            } else {
                const int t0 = tb + mf*16 + 4*g;
                u16x4 v = { bfbits(acc[mf][nf][0]), bfbits(acc[mf][nf][1]),
                            bfbits(acc[mf][nf][2]), bfbits(acc[mf][nf][3]) };
                *(u16x4*)(VT + ((size_t)bb * DH + np) * DT + t0) = v;
            }
        }
}

// Causal flash attention. 4 waves/block cooperating on one 16-row q-tile:
// wave w handles kv-tiles w, w+4, ... with private online-softmax state,
// then partials merge through LDS in two h-halves (17.5 KB LDS).
__global__ __launch_bounds__(256, 2) void attn_kernel(const unsigned short* __restrict__ Qb,
                                                      const unsigned short* __restrict__ Kb,
                                                      const unsigned short* __restrict__ VT,
                                                      float* __restrict__ out){
    __shared__ float facc[4 * 16 * 68];
    __shared__ float sm[64];
    __shared__ float sl[64];

    const int tid  = threadIdx.x;
    const int lane = tid & 63;
    const int w    = tid >> 6;
    const int g = lane >> 4, c = lane & 15;
    const int bi = blockIdx.x;
    // largest causal tiles first: bi 0..7 -> qt=127 (all batches), etc.
    const int b  = bi & 7;
    const int qt = 127 - (bi >> 3);
    const int q0 = qt * 16;
    const int q  = q0 + c;

    short8 qf[4];
#pragma unroll
    for (int hc = 0; hc < 4; ++hc)
        qf[hc] = *(const short8*)(Qb + ((size_t)b*DT + q0 + c) * DH + hc*32 + g*8);

    f32x4 acc[8] = {};
    float m = -1e30f, l = 0.f;
    const int ntiles = (q0 + 16 + 31) >> 5;

    for (int kt = w; kt < ntiles; kt += 4){
        const int kv0 = kt * 32;
        f32x4 s0 = {0.f,0.f,0.f,0.f}, s1 = {0.f,0.f,0.f,0.f};
        __builtin_amdgcn_s_setprio(1);
#pragma unroll
        for (int hc = 0; hc < 4; ++hc){
            short8 kf0 = *(const short8*)(Kb + ((size_t)b*DT + kv0 +      c) * DH + hc*32 + g*8);
            short8 kf1 = *(const short8*)(Kb + ((size_t)b*DT + kv0 + 16 + c) * DH + hc*32 + g*8);
            s0 = __builtin_amdgcn_mfma_f32_16x16x32_bf16(kf0, qf[hc], s0, 0,0,0);
            s1 = __builtin_amdgcn_mfma_f32_16x16x32_bf16(kf1, qf[hc], s1, 0,0,0);
        }
        __builtin_amdgcn_s_setprio(0);
        if (kv0 + 31 > q0){
#pragma unroll
            for (int r = 0; r < 4; ++r){
                if (kv0 +      4*g + r > q) s0[r] = -1e30f;
                if (kv0 + 16 + 4*g + r > q) s1[r] = -1e30f;
            }
        }
        float tm = fmaxf(fmaxf(fmaxf(s0[0], s0[1]), fmaxf(s0[2], s0[3])),
                         fmaxf(fmaxf(s1[0], s1[1]), fmaxf(s1[2], s1[3])));
        tm = fmaxf(tm, __shfl_xor(tm, 16));
        tm = fmaxf(tm, __shfl_xor(tm, 32));
        const float mn = fmaxf(m, tm);
        const float rs = exp2f(m - mn);
        float p0[4], p1[4]; float ps = 0.f;
#pragma unroll
        for (int r = 0; r < 4; ++r){
            p0[r] = exp2f(s0[r] - mn);
            p1[r] = exp2f(s1[r] - mn);
            ps += p0[r] + p1[r];
        }
        ps += __shfl_xor(ps, 16);
        ps += __shfl_xor(ps, 32);
        l = l * rs + ps; m = mn;
#pragma unroll
        for (int mt = 0; mt < 8; ++mt) acc[mt] *= rs;

        // Redistribute P (S^T D-layout) into PV B-fragment layout (kv = 8g+i).
        const unsigned pk0 = pbf2(p0[0], p0[1]), pk1 = pbf2(p0[2], p0[3]);
        const unsigned pk2 = pbf2(p1[0], p1[1]), pk3 = pbf2(p1[2], p1[3]);
        const int src0 = c + (((2*g    ) & 3) << 4);
        const int src1 = c + (((2*g + 1) & 3) << 4);
        const int sel  = g >> 1;
        unsigned a0 = __shfl(pk0, src0), a2 = __shfl(pk2, src0);
        unsigned b0 = __shfl(pk1, src0), b2 = __shfl(pk3, src0);
        unsigned c0 = __shfl(pk0, src1), c2 = __shfl(pk2, src1);
        unsigned d0 = __shfl(pk1, src1), d2 = __shfl(pk3, src1);
        i32x4 pw = { (int)(sel ? a2 : a0), (int)(sel ? b2 : b0),
                     (int)(sel ? c2 : c0), (int)(sel ? d2 : d0) };
        short8 pf = __builtin_bit_cast(short8, pw);
        __builtin_amdgcn_s_setprio(1);
#pragma unroll
        for (int mt = 0; mt < 8; ++mt){
            short8 vf = *(const short8*)(VT + ((size_t)b*DH + mt*16 + c) * DT + kv0 + g*8);
            acc[mt] = __builtin_amdgcn_mfma_f32_16x16x32_bf16(vf, pf, acc[mt], 0,0,0);
        }
        __builtin_amdgcn_s_setprio(0);
    }

    // ---- merge the 4 per-wave partials (two h-halves to halve LDS) ----
    if (g == 0) sm[w*16 + c] = m;
    __syncthreads();
    const float M = fmaxf(fmaxf(sm[c], sm[16 + c]), fmaxf(sm[32 + c], sm[48 + c]));
    const float scale = exp2f(m - M);          // 0 for idle waves (m = -1e30)
    if (g == 0) sl[w*16 + c] = l * scale;

    float inv = 0.f;
    float* orow = out + ((size_t)b*DT + q0 + c) * DH;
#pragma unroll
    for (int ph = 0; ph < 2; ++ph){
#pragma unroll
        for (int mt = 0; mt < 4; ++mt){
            f32x4 v = acc[ph*4 + mt] * scale;
            *(f32x4*)&facc[(w*16 + c) * 68 + mt*16 + 4*g] = v;
        }
        __syncthreads();
        if (ph == 0){
            const float L = sl[c] + sl[16 + c] + sl[32 + c] + sl[48 + c];
            inv = 1.0f / L;
        }
        const int ho = w*16 + g*4;             // 0..60, col within this half
        f32x4 s = {0.f,0.f,0.f,0.f};
#pragma unroll
        for (int w2 = 0; w2 < 4; ++w2)
            s += *(const f32x4*)&facc[(w2*16 + c) * 68 + ho];
        s *= inv;
        *(f32x4*)(orow + ph*64 + ho) = s;
        if (ph == 0) __syncthreads();
    }
}

extern "C" void kernel_launch(void* const* d_in, const int* in_sizes, int n_in,
                              void* d_out, int out_size, void* d_ws, size_t ws_size,
                              hipStream_t stream){
    const float* x  = (const float*)d_in[0];
    const float* Wq = (const float*)d_in[1];
    const float* Wk = (const float*)d_in[2];
    const float* Wv = (const float*)d_in[3];
    float* out = (float*)d_out;

    unsigned short* WT = (unsigned short*)d_ws;          // [384][1024] bf16
    unsigned short* Qb = WT + 3 * DH * DC;               // [B*T][H]
    unsigned short* Kb = Qb + (size_t)DB * DT * DH;      // [B*T][H]
    unsigned short* VT = Kb + (size_t)DB * DT * DH;      // [B][H][T]

    hipLaunchKernelGGL(prep_wt_kernel, dim3(1536), dim3(256), 0, stream, Wq, Wk, Wv, WT);
    hipLaunchKernelGGL(qkv_kernel, dim3(512), dim3(512), 0, stream, x, WT, Qb, Kb, VT);
    hipLaunchKernelGGL(attn_kernel, dim3(DB * (DT / 16)), dim3(256), 0, stream, Qb, Kb, VT, out);
}

// Round 5
// 133.244 us; speedup vs baseline: 2.2647x; 1.0442x over previous
//
#include <hip/hip_runtime.h>
#include <hip/hip_bf16.h>

#define DB 8
#define DT 2048
#define DC 1024
#define DH 128

typedef __attribute__((ext_vector_type(8))) short short8;
typedef __attribute__((ext_vector_type(4))) float f32x4;
typedef __attribute__((ext_vector_type(4))) int i32x4;
typedef __attribute__((ext_vector_type(4))) unsigned short u16x4;

// round-to-nearest-even f32 -> bf16 bits
static __device__ __forceinline__ unsigned short bfbits(float x){
    union { float f; unsigned u; } a; a.f = x;
    unsigned u = a.u;
    unsigned r = u + 0x7fffu + ((u >> 16) & 1u);
    return (unsigned short)(r >> 16);
}
static __device__ __forceinline__ unsigned pbf2(float lo, float hi){
    return (unsigned)bfbits(lo) | ((unsigned)bfbits(hi) << 16);
}

// Redistribute 32 kv-wide P slice (S^T D-layout words pk0..pk3) into the
// PV B-fragment layout (kv = 8g+i). Verified in R0.
static __device__ __forceinline__ short8 redist(unsigned pk0, unsigned pk1,
                                                unsigned pk2, unsigned pk3,
                                                int g, int c){
    const int src0 = c + (((2*g    ) & 3) << 4);
    const int src1 = c + (((2*g + 1) & 3) << 4);
    const int sel  = g >> 1;
    unsigned a0 = __shfl(pk0, src0), a2 = __shfl(pk2, src0);
    unsigned b0 = __shfl(pk1, src0), b2 = __shfl(pk3, src0);
    unsigned c0 = __shfl(pk0, src1), c2 = __shfl(pk2, src1);
    unsigned d0 = __shfl(pk1, src1), d2 = __shfl(pk3, src1);
    i32x4 pw = { (int)(sel ? a2 : a0), (int)(sel ? b2 : b0),
                 (int)(sel ? c2 : c0), (int)(sel ? d2 : d0) };
    return __builtin_bit_cast(short8, pw);
}

// WT[p][n][k] = W_p[k][n] (bf16) == flat [384][1024]; scale*log2e folded into Wq
__global__ __launch_bounds__(256) void prep_wt_kernel(const float* __restrict__ Wq,
                                                      const float* __restrict__ Wk,
                                                      const float* __restrict__ Wv,
                                                      unsigned short* __restrict__ WT){
    int gid = blockIdx.x * 256 + threadIdx.x;      // 0 .. 3*128*1024-1
    int p   = gid >> 17;
    int rem = gid & 131071;
    int n   = rem >> 10;
    int k   = rem & 1023;
    const float* W = (p == 0) ? Wq : (p == 1 ? Wk : Wv);
    float v = W[(size_t)k * DH + n];
    if (p == 0) v *= 0.08838834764831845f * 1.4426950408889634f;  // H^-0.5 * log2(e)
    WT[gid] = bfbits(v);
}

// Fused QKV projection, LDS-staged (unchanged from R3/R4 passing version).
#define QBK 64
#define QLDW 72
__global__ __launch_bounds__(512, 4) void qkv_kernel(const float* __restrict__ x,
                                                     const unsigned short* __restrict__ WT,
                                                     unsigned short* __restrict__ Qb,
                                                     unsigned short* __restrict__ Kb,
                                                     unsigned short* __restrict__ VT){
    __shared__ unsigned short xs[2 * 32 * QLDW];

    const int tid  = threadIdx.x;
    const int lane = tid & 63;
    const int w    = tid >> 6;            // 0..7
    const int g = lane >> 4, c = lane & 15;
    const int m0 = blockIdx.x * 32;
    const int n0 = w * 48;

    const int sr = tid >> 4;              // row 0..31
    const int sc = (tid & 15) * 4;        // f32 col 0..60
    const float* xg = x + (size_t)(m0 + sr) * DC + sc;
    unsigned short* xw = xs + sr * QLDW + sc;

    f32x4 acc[2][3] = {};

    {
        float4 v = *(const float4*)xg;
        u16x4 h = { bfbits(v.x), bfbits(v.y), bfbits(v.z), bfbits(v.w) };
        *(u16x4*)xw = h;
    }

    for (int t = 0; t < DC / QBK; ++t){
        const int cur = t & 1;
        __syncthreads();
        float4 nv;
        if (t < DC / QBK - 1)
            nv = *(const float4*)(xg + (t + 1) * QBK);
        const unsigned short* xr = xs + cur * (32 * QLDW);
#pragma unroll
        for (int kk = 0; kk < 2; ++kk){
            short8 bfr[3], af[2];
#pragma unroll
            for (int nf = 0; nf < 3; ++nf)
                bfr[nf] = *(const short8*)(WT + (size_t)(n0 + nf*16 + c) * DC + t*QBK + kk*32 + g*8);
#pragma unroll
            for (int mf = 0; mf < 2; ++mf)
                af[mf] = *(const short8*)(xr + (mf*16 + c) * QLDW + kk*32 + g*8);
#pragma unroll
            for (int mf = 0; mf < 2; ++mf)
#pragma unroll
                for (int nf = 0; nf < 3; ++nf)
                    acc[mf][nf] = __builtin_amdgcn_mfma_f32_16x16x32_bf16(af[mf], bfr[nf], acc[mf][nf], 0, 0, 0);
        }
        if (t < DC / QBK - 1){
            u16x4 h = { bfbits(nv.x), bfbits(nv.y), bfbits(nv.z), bfbits(nv.w) };
            *(u16x4*)(xw + (1 - cur) * (32 * QLDW)) = h;
        }
    }

    const int bb = m0 >> 11;
    const int tb = m0 & 2047;
#pragma unroll
    for (int mf = 0; mf < 2; ++mf)
#pragma unroll
        for (int nf = 0; nf < 3; ++nf){
            const int n  = n0 + nf*16;
            const int p  = n >> 7;
            const int np = (n & 127) + c;
            const int row = m0 + mf*16 + 4*g;
            if (p < 2){
                unsigned short* O = (p == 0) ? Qb : Kb;   // [B*T][H]
#pragma unroll
                for (int r = 0; r < 4; ++r)
                    O[(size_t)(row + r) * DH + np] = bfbits(acc[mf][nf][r]);
            } else {
                const int t0 = tb + mf*16 + 4*g;
                u16x4 v = { bfbits(acc[mf][nf][0]), bfbits(acc[mf][nf][1]),
                            bfbits(acc[mf][nf][2]), bfbits(acc[mf][nf][3]) };
                *(u16x4*)(VT + ((size_t)bb * DH + np) * DT + t0) = v;
            }
        }
}

// Causal flash attention. 4 waves/block on one 16-row q-tile, kv-split by 4,
// KVBLK=64 (4 S-tiles / 16 QK MFMA / 16 PV MFMA per softmax pass).
// V fragments issued early so their latency hides under the softmax chain.
__global__ __launch_bounds__(256, 2) void attn_kernel(const unsigned short* __restrict__ Qb,
                                                      const unsigned short* __restrict__ Kb,
                                                      const unsigned short* __restrict__ VT,
                                                      float* __restrict__ out){
    __shared__ float facc[4 * 16 * 68];
    __shared__ float sm[64];
    __shared__ float sl[64];

    const int tid  = threadIdx.x;
    const int lane = tid & 63;
    const int w    = tid >> 6;
    const int g = lane >> 4, c = lane & 15;
    const int bi = blockIdx.x;
    // largest causal tiles first; batch pinned to bi&7 (XCD affinity)
    const int b  = bi & 7;
    const int qt = 127 - (bi >> 3);
    const int q0 = qt * 16;
    const int q  = q0 + c;

    short8 qf[4];
#pragma unroll
    for (int hc = 0; hc < 4; ++hc)
        qf[hc] = *(const short8*)(Qb + ((size_t)b*DT + q0 + c) * DH + hc*32 + g*8);

    f32x4 acc[8] = {};
    float m = -1e30f, l = 0.f;
    const int nt = (q0 + 79) >> 6;        // ceil((q0+16)/64)

    for (int kt = w; kt < nt; kt += 4){
        const int kv0 = kt * 64;

        // ---- QK^T: 4 S-tiles (16 kv rows each) ----
        f32x4 s[4] = {};
        short8 kf[4][4];
#pragma unroll
        for (int j = 0; j < 4; ++j)
#pragma unroll
            for (int hc = 0; hc < 4; ++hc)
                kf[j][hc] = *(const short8*)(Kb + ((size_t)b*DT + kv0 + 16*j + c) * DH + hc*32 + g*8);
        __builtin_amdgcn_s_setprio(1);
#pragma unroll
        for (int hc = 0; hc < 4; ++hc)
#pragma unroll
            for (int j = 0; j < 4; ++j)
                s[j] = __builtin_amdgcn_mfma_f32_16x16x32_bf16(kf[j][hc], qf[hc], s[j], 0,0,0);
        __builtin_amdgcn_s_setprio(0);

        // ---- issue V fragments early (latency hides under softmax) ----
        short8 vf0[8], vf1[8];
#pragma unroll
        for (int mt = 0; mt < 8; ++mt){
            const unsigned short* vp = VT + ((size_t)b*DH + mt*16 + c) * DT + kv0 + g*8;
            vf0[mt] = *(const short8*)vp;
            vf1[mt] = *(const short8*)(vp + 32);
        }

        // ---- causal mask ----
        if (kv0 + 63 > q0){
#pragma unroll
            for (int j = 0; j < 4; ++j){
                const int o = kv0 + 16*j + 4*g;
#pragma unroll
                for (int r = 0; r < 4; ++r)
                    if (o + r > q) s[j][r] = -1e30f;
            }
        }

        // ---- online softmax over 16 values + cross-lane ----
        float tm = -1e30f;
#pragma unroll
        for (int j = 0; j < 4; ++j)
#pragma unroll
            for (int r = 0; r < 4; ++r) tm = fmaxf(tm, s[j][r]);
        tm = fmaxf(tm, __shfl_xor(tm, 16));
        tm = fmaxf(tm, __shfl_xor(tm, 32));
        const float mn = fmaxf(m, tm);
        const float rs = exp2f(m - mn);
        float p[4][4]; float ps = 0.f;
#pragma unroll
        for (int j = 0; j < 4; ++j)
#pragma unroll
            for (int r = 0; r < 4; ++r){
                p[j][r] = exp2f(s[j][r] - mn);
                ps += p[j][r];
            }
        ps += __shfl_xor(ps, 16);
        ps += __shfl_xor(ps, 32);
        l = l * rs + ps; m = mn;
#pragma unroll
        for (int mt = 0; mt < 8; ++mt) acc[mt] *= rs;

        // ---- P -> B-fragment layout, two 32-wide halves ----
        short8 pf0 = redist(pbf2(p[0][0], p[0][1]), pbf2(p[0][2], p[0][3]),
                            pbf2(p[1][0], p[1][1]), pbf2(p[1][2], p[1][3]), g, c);
        short8 pf1 = redist(pbf2(p[2][0], p[2][1]), pbf2(p[2][2], p[2][3]),
                            pbf2(p[3][0], p[3][1]), pbf2(p[3][2], p[3][3]), g, c);

        // ---- PV ----
        __builtin_amdgcn_s_setprio(1);
#pragma unroll
        for (int mt = 0; mt < 8; ++mt){
            acc[mt] = __builtin_amdgcn_mfma_f32_16x16x32_bf16(vf0[mt], pf0, acc[mt], 0,0,0);
            acc[mt] = __builtin_amdgcn_mfma_f32_16x16x32_bf16(vf1[mt], pf1, acc[mt], 0,0,0);
        }
        __builtin_amdgcn_s_setprio(0);
    }

    // ---- merge the 4 per-wave partials (two h-halves, 17.5 KB LDS) ----
    if (g == 0) sm[w*16 + c] = m;
    __syncthreads();
    const float M = fmaxf(fmaxf(sm[c], sm[16 + c]), fmaxf(sm[32 + c], sm[48 + c]));
    const float scale = exp2f(m - M);          // 0 for idle waves (m = -1e30)
    if (g == 0) sl[w*16 + c] = l * scale;

    float inv = 0.f;
    float* orow = out + ((size_t)b*DT + q0 + c) * DH;
#pragma unroll
    for (int ph = 0; ph < 2; ++ph){
#pragma unroll
        for (int mt = 0; mt < 4; ++mt){
            f32x4 v = acc[ph*4 + mt] * scale;
            *(f32x4*)&facc[(w*16 + c) * 68 + mt*16 + 4*g] = v;
        }
        __syncthreads();
        if (ph == 0){
            const float L = sl[c] + sl[16 + c] + sl[32 + c] + sl[48 + c];
            inv = 1.0f / L;
        }
        const int ho = w*16 + g*4;
        f32x4 s = {0.f,0.f,0.f,0.f};
#pragma unroll
        for (int w2 = 0; w2 < 4; ++w2)
            s += *(const f32x4*)&facc[(w2*16 + c) * 68 + ho];
        s *= inv;
        *(f32x4*)(orow + ph*64 + ho) = s;
        if (ph == 0) __syncthreads();
    }
}

extern "C" void kernel_launch(void* const* d_in, const int* in_sizes, int n_in,
                              void* d_out, int out_size, void* d_ws, size_t ws_size,
                              hipStream_t stream){
    const float* x  = (const float*)d_in[0];
    const float* Wq = (const float*)d_in[1];
    const float* Wk = (const float*)d_in[2];
    const float* Wv = (const float*)d_in[3];
    float* out = (float*)d_out;

    unsigned short* WT = (unsigned short*)d_ws;          // [384][1024] bf16
    unsigned short* Qb = WT + 3 * DH * DC;               // [B*T][H]
    unsigned short* Kb = Qb + (size_t)DB * DT * DH;      // [B*T][H]
    unsigned short* VT = Kb + (size_t)DB * DT * DH;      // [B][H][T]

    hipLaunchKernelGGL(prep_wt_kernel, dim3(1536), dim3(256), 0, stream, Wq, Wk, Wv, WT);
    hipLaunchKernelGGL(qkv_kernel, dim3(512), dim3(512), 0, stream, x, WT, Qb, Kb, VT);
    hipLaunchKernelGGL(attn_kernel, dim3(DB * (DT / 16)), dim3(256), 0, stream, Qb, Kb, VT, out);
}

// Round 6
// 120.823 us; speedup vs baseline: 2.4975x; 1.1028x over previous
//
#include <hip/hip_runtime.h>
#include <hip/hip_bf16.h>

#define DB 8
#define DT 2048
#define DC 1024
#define DH 128

typedef __attribute__((ext_vector_type(8))) short short8;
typedef __attribute__((ext_vector_type(4))) float f32x4;
typedef __attribute__((ext_vector_type(4))) int i32x4;
typedef __attribute__((ext_vector_type(4))) unsigned short u16x4;

// round-to-nearest-even f32 -> bf16 bits
static __device__ __forceinline__ unsigned short bfbits(float x){
    union { float f; unsigned u; } a; a.f = x;
    unsigned u = a.u;
    unsigned r = u + 0x7fffu + ((u >> 16) & 1u);
    return (unsigned short)(r >> 16);
}
static __device__ __forceinline__ unsigned pbf2(float lo, float hi){
    return (unsigned)bfbits(lo) | ((unsigned)bfbits(hi) << 16);
}

// Redistribute 32 kv-wide P slice (S^T D-layout words pk0..pk3) into the
// PV B-fragment layout (kv = 8g+i). Verified R0..R5.
static __device__ __forceinline__ short8 redist(unsigned pk0, unsigned pk1,
                                                unsigned pk2, unsigned pk3,
                                                int g, int c){
    const int src0 = c + (((2*g    ) & 3) << 4);
    const int src1 = c + (((2*g + 1) & 3) << 4);
    const int sel  = g >> 1;
    unsigned a0 = __shfl(pk0, src0), a2 = __shfl(pk2, src0);
    unsigned b0 = __shfl(pk1, src0), b2 = __shfl(pk3, src0);
    unsigned c0 = __shfl(pk0, src1), c2 = __shfl(pk2, src1);
    unsigned d0 = __shfl(pk1, src1), d2 = __shfl(pk3, src1);
    i32x4 pw = { (int)(sel ? a2 : a0), (int)(sel ? b2 : b0),
                 (int)(sel ? c2 : c0), (int)(sel ? d2 : d0) };
    return __builtin_bit_cast(short8, pw);
}

// WT[p][n][k] = W_p[k][n] (bf16) == flat [384][1024]; scale*log2e folded into Wq
__global__ __launch_bounds__(256) void prep_wt_kernel(const float* __restrict__ Wq,
                                                      const float* __restrict__ Wk,
                                                      const float* __restrict__ Wv,
                                                      unsigned short* __restrict__ WT){
    int gid = blockIdx.x * 256 + threadIdx.x;      // 0 .. 3*128*1024-1
    int p   = gid >> 17;
    int rem = gid & 131071;
    int n   = rem >> 10;
    int k   = rem & 1023;
    const float* W = (p == 0) ? Wq : (p == 1 ? Wk : Wv);
    float v = W[(size_t)k * DH + n];
    if (p == 0) v *= 0.08838834764831845f * 1.4426950408889634f;  // H^-0.5 * log2(e)
    WT[gid] = bfbits(v);
}

// Fused QKV projection, LDS-staged (unchanged from R4/R5 passing version).
#define QBK 64
#define QLDW 72
__global__ __launch_bounds__(512, 4) void qkv_kernel(const float* __restrict__ x,
                                                     const unsigned short* __restrict__ WT,
                                                     unsigned short* __restrict__ Qb,
                                                     unsigned short* __restrict__ Kb,
                                                     unsigned short* __restrict__ VT){
    __shared__ unsigned short xs[2 * 32 * QLDW];

    const int tid  = threadIdx.x;
    const int lane = tid & 63;
    const int w    = tid >> 6;            // 0..7
    const int g = lane >> 4, c = lane & 15;
    const int m0 = blockIdx.x * 32;
    const int n0 = w * 48;

    const int sr = tid >> 4;              // row 0..31
    const int sc = (tid & 15) * 4;        // f32 col 0..60
    const float* xg = x + (size_t)(m0 + sr) * DC + sc;
    unsigned short* xw = xs + sr * QLDW + sc;

    f32x4 acc[2][3] = {};

    {
        float4 v = *(const float4*)xg;
        u16x4 h = { bfbits(v.x), bfbits(v.y), bfbits(v.z), bfbits(v.w) };
        *(u16x4*)xw = h;
    }

    for (int t = 0; t < DC / QBK; ++t){
        const int cur = t & 1;
        __syncthreads();
        float4 nv;
        if (t < DC / QBK - 1)
            nv = *(const float4*)(xg + (t + 1) * QBK);
        const unsigned short* xr = xs + cur * (32 * QLDW);
#pragma unroll
        for (int kk = 0; kk < 2; ++kk){
            short8 bfr[3], af[2];
#pragma unroll
            for (int nf = 0; nf < 3; ++nf)
                bfr[nf] = *(const short8*)(WT + (size_t)(n0 + nf*16 + c) * DC + t*QBK + kk*32 + g*8);
#pragma unroll
            for (int mf = 0; mf < 2; ++mf)
                af[mf] = *(const short8*)(xr + (mf*16 + c) * QLDW + kk*32 + g*8);
#pragma unroll
            for (int mf = 0; mf < 2; ++mf)
#pragma unroll
                for (int nf = 0; nf < 3; ++nf)
                    acc[mf][nf] = __builtin_amdgcn_mfma_f32_16x16x32_bf16(af[mf], bfr[nf], acc[mf][nf], 0, 0, 0);
        }
        if (t < DC / QBK - 1){
            u16x4 h = { bfbits(nv.x), bfbits(nv.y), bfbits(nv.z), bfbits(nv.w) };
            *(u16x4*)(xw + (1 - cur) * (32 * QLDW)) = h;
        }
    }

    const int bb = m0 >> 11;
    const int tb = m0 & 2047;
#pragma unroll
    for (int mf = 0; mf < 2; ++mf)
#pragma unroll
        for (int nf = 0; nf < 3; ++nf){
            const int n  = n0 + nf*16;
            const int p  = n >> 7;
            const int np = (n & 127) + c;
            const int row = m0 + mf*16 + 4*g;
            if (p < 2){
                unsigned short* O = (p == 0) ? Qb : Kb;   // [B*T][H]
#pragma unroll
                for (int r = 0; r < 4; ++r)
                    O[(size_t)(row + r) * DH + np] = bfbits(acc[mf][nf][r]);
            } else {
                const int t0 = tb + mf*16 + 4*g;
                u16x4 v = { bfbits(acc[mf][nf][0]), bfbits(acc[mf][nf][1]),
                            bfbits(acc[mf][nf][2]), bfbits(acc[mf][nf][3]) };
                *(u16x4*)(VT + ((size_t)bb * DH + np) * DT + t0) = v;
            }
        }
}

// Causal flash attention, shared-LDS structure.
// Block = 64 q-rows (4 waves x 16 rows), grid 256 (1/CU), batch = bi&7 (XCD pin).
// Per kv-tile (64 rows): K[64][128] + V^T[128][64] bf16 staged to LDS by all
// 256 threads (double-buffered, T14 reg-staged, T2 XOR-swizzled); consumed by
// all 4 waves. No cross-wave merge: each wave owns complete rows.
__global__ __launch_bounds__(256, 2) void attn_kernel(const unsigned short* __restrict__ Qb,
                                                      const unsigned short* __restrict__ Kb,
                                                      const unsigned short* __restrict__ VT,
                                                      float* __restrict__ out){
    __shared__ unsigned char lds[2][32768];   // per buf: K 16KB @0, V 16KB @16384

    const int tid  = threadIdx.x;
    const int lane = tid & 63;
    const int w    = tid >> 6;
    const int g = lane >> 4, c = lane & 15;
    const int bi = blockIdx.x;
    const int b  = bi & 7;                 // batch == XCD (bi % 8)
    const int qt = 31 - (bi >> 3);         // largest first
    const int q0 = qt * 64;
    const int qw = q0 + 16 * w;            // this wave's q-tile base
    const int q  = qw + c;                 // this lane's q row

    const unsigned short* Kbase = Kb + (size_t)b * DT * DH;
    const unsigned short* Vbase = VT + (size_t)b * DH * DT;

    short8 qf[4];
#pragma unroll
    for (int hc = 0; hc < 4; ++hc)
        qf[hc] = *(const short8*)(Qb + ((size_t)b*DT + qw + c) * DH + hc*32 + g*8);

    f32x4 acc[8] = {};
    float m = -1e30f, l = 0.f;

    i32x4 kreg[4], vreg[4];
    // ---- prologue: stage tile 0 ----
#pragma unroll
    for (int p = 0; p < 4; ++p){
        const int s = p*256 + tid;
        kreg[p] = *(const i32x4*)(Kbase + (size_t)(s >> 4) * DH + (s & 15) * 8);
        vreg[p] = *(const i32x4*)(Vbase + (size_t)(s >> 3) * DT + (s & 7) * 8);
    }
#pragma unroll
    for (int p = 0; p < 4; ++p){
        const int s = p*256 + tid;
        const int r = s >> 4, cb = (s & 15) * 16;
        *(i32x4*)(lds[0] + r*256 + (cb ^ ((r & 7) << 4))) = kreg[p];
        const int h = s >> 3, tb = (s & 7) * 16;
        *(i32x4*)(lds[0] + 16384 + h*128 + (tb ^ ((h & 7) << 4))) = vreg[p];
    }

    for (int kt = 0; kt <= qt; ++kt){
        const int cur = kt & 1;
        const int kv0 = kt * 64;
        __syncthreads();                          // buf[cur] staged & prior reads done

        // ---- issue next tile's global loads early (T14) ----
        if (kt < qt){
            const int nv0 = kv0 + 64;
#pragma unroll
            for (int p = 0; p < 4; ++p){
                const int s = p*256 + tid;
                kreg[p] = *(const i32x4*)(Kbase + (size_t)(nv0 + (s >> 4)) * DH + (s & 15) * 8);
                vreg[p] = *(const i32x4*)(Vbase + (size_t)(s >> 3) * DT + nv0 + (s & 7) * 8);
            }
        }

        const unsigned char* kb = lds[cur];
        const unsigned char* vb = lds[cur] + 16384;

        // ---- QK^T from LDS K ----
        f32x4 s4[4] = {};
        short8 kf[4][4];
#pragma unroll
        for (int j = 0; j < 4; ++j){
            const int r = 16*j + c;
#pragma unroll
            for (int hc = 0; hc < 4; ++hc)
                kf[j][hc] = *(const short8*)(kb + r*256 + ((hc*64 + g*16) ^ ((r & 7) << 4)));
        }
        __builtin_amdgcn_s_setprio(1);
#pragma unroll
        for (int hc = 0; hc < 4; ++hc)
#pragma unroll
            for (int j = 0; j < 4; ++j)
                s4[j] = __builtin_amdgcn_mfma_f32_16x16x32_bf16(kf[j][hc], qf[hc], s4[j], 0,0,0);
        __builtin_amdgcn_s_setprio(0);

        // ---- causal mask (only possible on the last tile) ----
        if (kt == qt){
#pragma unroll
            for (int j = 0; j < 4; ++j){
                const int o = kv0 + 16*j + 4*g;
#pragma unroll
                for (int r = 0; r < 4; ++r)
                    if (o + r > q) s4[j][r] = -1e30f;
            }
        }

        // ---- online softmax (per wave, rows uniform in c across g) ----
        float tm = -1e30f;
#pragma unroll
        for (int j = 0; j < 4; ++j)
#pragma unroll
            for (int r = 0; r < 4; ++r) tm = fmaxf(tm, s4[j][r]);
        tm = fmaxf(tm, __shfl_xor(tm, 16));
        tm = fmaxf(tm, __shfl_xor(tm, 32));
        const float mn = fmaxf(m, tm);
        const float rs = exp2f(m - mn);
        float p[4][4]; float ps = 0.f;
#pragma unroll
        for (int j = 0; j < 4; ++j)
#pragma unroll
            for (int r = 0; r < 4; ++r){
                p[j][r] = exp2f(s4[j][r] - mn);
                ps += p[j][r];
            }
        ps += __shfl_xor(ps, 16);
        ps += __shfl_xor(ps, 32);
        l = l * rs + ps; m = mn;
#pragma unroll
        for (int mt = 0; mt < 8; ++mt) acc[mt] *= rs;

        // ---- P -> B-fragment layout, two 32-wide halves ----
        short8 pf0 = redist(pbf2(p[0][0], p[0][1]), pbf2(p[0][2], p[0][3]),
                            pbf2(p[1][0], p[1][1]), pbf2(p[1][2], p[1][3]), g, c);
        short8 pf1 = redist(pbf2(p[2][0], p[2][1]), pbf2(p[2][2], p[2][3]),
                            pbf2(p[3][0], p[3][1]), pbf2(p[3][2], p[3][3]), g, c);

        // ---- PV from LDS V ----
#pragma unroll
        for (int kk = 0; kk < 2; ++kk){
            short8 vf[8];
#pragma unroll
            for (int mt = 0; mt < 8; ++mt){
                const int h = mt*16 + c;
                vf[mt] = *(const short8*)(vb + h*128 + ((kk*64 + g*16) ^ ((h & 7) << 4)));
            }
            const short8 pf = kk ? pf1 : pf0;
            __builtin_amdgcn_s_setprio(1);
#pragma unroll
            for (int mt = 0; mt < 8; ++mt)
                acc[mt] = __builtin_amdgcn_mfma_f32_16x16x32_bf16(vf[mt], pf, acc[mt], 0,0,0);
            __builtin_amdgcn_s_setprio(0);
        }

        // ---- write next tile into the other buffer (late, T14) ----
        if (kt < qt){
#pragma unroll
            for (int p2 = 0; p2 < 4; ++p2){
                const int s = p2*256 + tid;
                const int r = s >> 4, cb = (s & 15) * 16;
                *(i32x4*)(lds[cur ^ 1] + r*256 + (cb ^ ((r & 7) << 4))) = kreg[p2];
                const int h = s >> 3, tb = (s & 7) * 16;
                *(i32x4*)(lds[cur ^ 1] + 16384 + h*128 + (tb ^ ((h & 7) << 4))) = vreg[p2];
            }
        }
    }

    // ---- epilogue: direct normalized store (no merge needed) ----
    const float inv = 1.0f / l;
    float* orow = out + ((size_t)b*DT + q) * DH;
#pragma unroll
    for (int mt = 0; mt < 8; ++mt){
        f32x4 v = acc[mt] * inv;
        *(f32x4*)(orow + mt*16 + 4*g) = v;
    }
}

extern "C" void kernel_launch(void* const* d_in, const int* in_sizes, int n_in,
                              void* d_out, int out_size, void* d_ws, size_t ws_size,
                              hipStream_t stream){
    const float* x  = (const float*)d_in[0];
    const float* Wq = (const float*)d_in[1];
    const float* Wk = (const float*)d_in[2];
    const float* Wv = (const float*)d_in[3];
    float* out = (float*)d_out;

    unsigned short* WT = (unsigned short*)d_ws;          // [384][1024] bf16
    unsigned short* Qb = WT + 3 * DH * DC;               // [B*T][H]
    unsigned short* Kb = Qb + (size_t)DB * DT * DH;      // [B*T][H]
    unsigned short* VT = Kb + (size_t)DB * DT * DH;      // [B][H][T]

    hipLaunchKernelGGL(prep_wt_kernel, dim3(1536), dim3(256), 0, stream, Wq, Wk, Wv, WT);
    hipLaunchKernelGGL(qkv_kernel, dim3(512), dim3(512), 0, stream, x, WT, Qb, Kb, VT);
    hipLaunchKernelGGL(attn_kernel, dim3(DB * (DT / 64)), dim3(256), 0, stream, Qb, Kb, VT, out);
}

// Round 7
// 100.612 us; speedup vs baseline: 2.9992x; 1.2009x over previous
//
#include <hip/hip_runtime.h>
#include <hip/hip_bf16.h>

#define DB 8
#define DT 2048
#define DC 1024
#define DH 128

typedef __attribute__((ext_vector_type(8))) short short8;
typedef __attribute__((ext_vector_type(4))) float f32x4;
typedef __attribute__((ext_vector_type(4))) int i32x4;
typedef __attribute__((ext_vector_type(4))) unsigned short u16x4;

// round-to-nearest-even f32 -> bf16 bits
static __device__ __forceinline__ unsigned short bfbits(float x){
    union { float f; unsigned u; } a; a.f = x;
    unsigned u = a.u;
    unsigned r = u + 0x7fffu + ((u >> 16) & 1u);
    return (unsigned short)(r >> 16);
}
static __device__ __forceinline__ unsigned pbf2(float lo, float hi){
    return (unsigned)bfbits(lo) | ((unsigned)bfbits(hi) << 16);
}

// Redistribute 32 kv-wide P slice (S^T D-layout words pk0..pk3) into the
// PV B-fragment layout (kv = 8g+i). Verified R0..R6.
static __device__ __forceinline__ short8 redist(unsigned pk0, unsigned pk1,
                                                unsigned pk2, unsigned pk3,
                                                int g, int c){
    const int src0 = c + (((2*g    ) & 3) << 4);
    const int src1 = c + (((2*g + 1) & 3) << 4);
    const int sel  = g >> 1;
    unsigned a0 = __shfl(pk0, src0), a2 = __shfl(pk2, src0);
    unsigned b0 = __shfl(pk1, src0), b2 = __shfl(pk3, src0);
    unsigned c0 = __shfl(pk0, src1), c2 = __shfl(pk2, src1);
    unsigned d0 = __shfl(pk1, src1), d2 = __shfl(pk3, src1);
    i32x4 pw = { (int)(sel ? a2 : a0), (int)(sel ? b2 : b0),
                 (int)(sel ? c2 : c0), (int)(sel ? d2 : d0) };
    return __builtin_bit_cast(short8, pw);
}

// WTc[t][chunk][n][e] = W_p[k][h] bf16, k = t*32 + chunk*8 + e, n = p*128+h.
// k-chunk-major tile order => qkv B staging is load-coalesced and
// ds_write lane-linear. scale*log2e folded into Wq (p==0).
__global__ __launch_bounds__(256) void prep_wt_kernel(const float* __restrict__ Wq,
                                                      const float* __restrict__ Wk,
                                                      const float* __restrict__ Wv,
                                                      unsigned short* __restrict__ WTc){
    int gid = blockIdx.x * 256 + threadIdx.x;      // 0 .. 393215
    int e  = gid & 7;
    int F3 = gid >> 3;
    int n  = F3 % 384;
    int ct = F3 / 384;                              // t*4 + chunk, 0..127
    int k  = (ct >> 2) * 32 + (ct & 3) * 8 + e;
    int p  = n >> 7, h = n & 127;
    const float* W = (p == 0) ? Wq : (p == 1 ? Wk : Wv);
    float v = W[(size_t)k * DH + h];
    if (p == 0) v *= 0.08838834764831845f * 1.4426950408889634f;  // H^-0.5 * log2(e)
    WTc[gid] = bfbits(v);
}

// Fused QKV projection v2. BM=64 rows/block (grid 256), 512 threads (8 waves),
// wave w: 64 rows x 48 cols (acc 4x3), BK=32, both tiles LDS double-buffered.
// B-tile [4 chunks][384 n][8 elems] from WTc (coalesced loads, linear writes);
// A-tile row-major padded (stride 40) with f32->bf16 cvt on stage.
__global__ __launch_bounds__(512, 4) void qkv_kernel(const float* __restrict__ x,
                                                     const unsigned short* __restrict__ WTc,
                                                     unsigned short* __restrict__ Qb,
                                                     unsigned short* __restrict__ Kb,
                                                     unsigned short* __restrict__ VT){
    __shared__ unsigned short Bs[2][12288];   // 2 x 24KB
    __shared__ unsigned short As[2][2560];    // 2 x 5KB  (64 rows x stride 40)

    const int tid  = threadIdx.x;
    const int lane = tid & 63;
    const int w    = tid >> 6;
    const int g = lane >> 4, c = lane & 15;
    const int m0 = blockIdx.x * 64;
    const int n0 = w * 48;

    // B staging map: flat = j*512+tid in [0,1536) == chunk*384 + n
    const unsigned short* bsrc = WTc + (size_t)tid * 8;   // + j*4096 + t*12288
    // A staging map: threads 0..255, row = tid>>2, 8-elem chunk = tid&3
    const bool doA = tid < 256;
    const int arow = tid >> 2, ac8 = tid & 3;
    const float* asrc = x + (size_t)(m0 + arow) * DC + ac8 * 8;

    f32x4 acc[4][3] = {};
    i32x4 breg[3];
    float4 av0, av1;

    // ---- prologue: stage tile 0 ----
#pragma unroll
    for (int j = 0; j < 3; ++j)
        breg[j] = *(const i32x4*)(bsrc + j * 4096);
    if (doA){ av0 = *(const float4*)asrc; av1 = *(const float4*)(asrc + 4); }
#pragma unroll
    for (int j = 0; j < 3; ++j)
        *(i32x4*)(&Bs[0][j * 4096 + tid * 8]) = breg[j];
    if (doA){
        i32x4 h8 = { (int)pbf2(av0.x, av0.y), (int)pbf2(av0.z, av0.w),
                     (int)pbf2(av1.x, av1.y), (int)pbf2(av1.z, av1.w) };
        *(i32x4*)(&As[0][arow * 40 + ac8 * 8]) = h8;
    }

    for (int t = 0; t < DC / 32; ++t){
        const int cur = t & 1;
        __syncthreads();                          // buf[cur] staged, buf[cur^1] free
        // issue next tile's global loads early (T14)
        if (t < DC / 32 - 1){
#pragma unroll
            for (int j = 0; j < 3; ++j)
                breg[j] = *(const i32x4*)(bsrc + (t + 1) * 12288 + j * 4096);
            if (doA){
                av0 = *(const float4*)(asrc + (t + 1) * 32);
                av1 = *(const float4*)(asrc + (t + 1) * 32 + 4);
            }
        }
        // compute from buf[cur]
        short8 af[4], bfr[3];
#pragma unroll
        for (int mf = 0; mf < 4; ++mf)
            af[mf] = *(const short8*)(&As[cur][(mf*16 + c) * 40 + g * 8]);
#pragma unroll
        for (int nf = 0; nf < 3; ++nf)
            bfr[nf] = *(const short8*)(&Bs[cur][g * 3072 + (n0 + nf*16 + c) * 8]);
#pragma unroll
        for (int mf = 0; mf < 4; ++mf)
#pragma unroll
            for (int nf = 0; nf < 3; ++nf)
                acc[mf][nf] = __builtin_amdgcn_mfma_f32_16x16x32_bf16(af[mf], bfr[nf], acc[mf][nf], 0, 0, 0);
        // write next tile into the other buffer (late)
        if (t < DC / 32 - 1){
#pragma unroll
            for (int j = 0; j < 3; ++j)
                *(i32x4*)(&Bs[cur ^ 1][j * 4096 + tid * 8]) = breg[j];
            if (doA){
                i32x4 h8 = { (int)pbf2(av0.x, av0.y), (int)pbf2(av0.z, av0.w),
                             (int)pbf2(av1.x, av1.y), (int)pbf2(av1.z, av1.w) };
                *(i32x4*)(&As[cur ^ 1][arow * 40 + ac8 * 8]) = h8;
            }
        }
    }

    const int bb = m0 >> 11;         // batch (64-row tiles never cross batch)
    const int tb = m0 & 2047;
#pragma unroll
    for (int mf = 0; mf < 4; ++mf)
#pragma unroll
        for (int nf = 0; nf < 3; ++nf){
            const int n  = n0 + nf*16;         // fused col base (16-aligned, single p)
            const int p  = n >> 7;
            const int np = (n & 127) + c;
            const int row = m0 + mf*16 + 4*g;
            if (p < 2){
                unsigned short* O = (p == 0) ? Qb : Kb;   // [B*T][H]
#pragma unroll
                for (int r = 0; r < 4; ++r)
                    O[(size_t)(row + r) * DH + np] = bfbits(acc[mf][nf][r]);
            } else {
                const int t0 = tb + mf*16 + 4*g;
                u16x4 v = { bfbits(acc[mf][nf][0]), bfbits(acc[mf][nf][1]),
                            bfbits(acc[mf][nf][2]), bfbits(acc[mf][nf][3]) };
                *(u16x4*)(VT + ((size_t)bb * DH + np) * DT + t0) = v;
            }
        }
}

// Causal flash attention, shared-LDS structure (unchanged from R6 passing version).
__global__ __launch_bounds__(256, 2) void attn_kernel(const unsigned short* __restrict__ Qb,
                                                      const unsigned short* __restrict__ Kb,
                                                      const unsigned short* __restrict__ VT,
                                                      float* __restrict__ out){
    __shared__ unsigned char lds[2][32768];   // per buf: K 16KB @0, V 16KB @16384

    const int tid  = threadIdx.x;
    const int lane = tid & 63;
    const int w    = tid >> 6;
    const int g = lane >> 4, c = lane & 15;
    const int bi = blockIdx.x;
    const int b  = bi & 7;                 // batch == XCD (bi % 8)
    const int qt = 31 - (bi >> 3);         // largest first
    const int q0 = qt * 64;
    const int qw = q0 + 16 * w;            // this wave's q-tile base
    const int q  = qw + c;                 // this lane's q row

    const unsigned short* Kbase = Kb + (size_t)b * DT * DH;
    const unsigned short* Vbase = VT + (size_t)b * DH * DT;

    short8 qf[4];
#pragma unroll
    for (int hc = 0; hc < 4; ++hc)
        qf[hc] = *(const short8*)(Qb + ((size_t)b*DT + qw + c) * DH + hc*32 + g*8);

    f32x4 acc[8] = {};
    float m = -1e30f, l = 0.f;

    i32x4 kreg[4], vreg[4];
    // ---- prologue: stage tile 0 ----
#pragma unroll
    for (int p = 0; p < 4; ++p){
        const int s = p*256 + tid;
        kreg[p] = *(const i32x4*)(Kbase + (size_t)(s >> 4) * DH + (s & 15) * 8);
        vreg[p] = *(const i32x4*)(Vbase + (size_t)(s >> 3) * DT + (s & 7) * 8);
    }
#pragma unroll
    for (int p = 0; p < 4; ++p){
        const int s = p*256 + tid;
        const int r = s >> 4, cb = (s & 15) * 16;
        *(i32x4*)(lds[0] + r*256 + (cb ^ ((r & 7) << 4))) = kreg[p];
        const int h = s >> 3, tb = (s & 7) * 16;
        *(i32x4*)(lds[0] + 16384 + h*128 + (tb ^ ((h & 7) << 4))) = vreg[p];
    }

    for (int kt = 0; kt <= qt; ++kt){
        const int cur = kt & 1;
        const int kv0 = kt * 64;
        __syncthreads();                          // buf[cur] staged & prior reads done

        // ---- issue next tile's global loads early (T14) ----
        if (kt < qt){
            const int nv0 = kv0 + 64;
#pragma unroll
            for (int p = 0; p < 4; ++p){
                const int s = p*256 + tid;
                kreg[p] = *(const i32x4*)(Kbase + (size_t)(nv0 + (s >> 4)) * DH + (s & 15) * 8);
                vreg[p] = *(const i32x4*)(Vbase + (size_t)(s >> 3) * DT + nv0 + (s & 7) * 8);
            }
        }

        const unsigned char* kb = lds[cur];
        const unsigned char* vb = lds[cur] + 16384;

        // ---- QK^T from LDS K ----
        f32x4 s4[4] = {};
        short8 kf[4][4];
#pragma unroll
        for (int j = 0; j < 4; ++j){
            const int r = 16*j + c;
#pragma unroll
            for (int hc = 0; hc < 4; ++hc)
                kf[j][hc] = *(const short8*)(kb + r*256 + ((hc*64 + g*16) ^ ((r & 7) << 4)));
        }
        __builtin_amdgcn_s_setprio(1);
#pragma unroll
        for (int hc = 0; hc < 4; ++hc)
#pragma unroll
            for (int j = 0; j < 4; ++j)
                s4[j] = __builtin_amdgcn_mfma_f32_16x16x32_bf16(kf[j][hc], qf[hc], s4[j], 0,0,0);
        __builtin_amdgcn_s_setprio(0);

        // ---- causal mask (only possible on the last tile) ----
        if (kt == qt){
#pragma unroll
            for (int j = 0; j < 4; ++j){
                const int o = kv0 + 16*j + 4*g;
#pragma unroll
                for (int r = 0; r < 4; ++r)
                    if (o + r > q) s4[j][r] = -1e30f;
            }
        }

        // ---- online softmax (per wave) ----
        float tm = -1e30f;
#pragma unroll
        for (int j = 0; j < 4; ++j)
#pragma unroll
            for (int r = 0; r < 4; ++r) tm = fmaxf(tm, s4[j][r]);
        tm = fmaxf(tm, __shfl_xor(tm, 16));
        tm = fmaxf(tm, __shfl_xor(tm, 32));
        const float mn = fmaxf(m, tm);
        const float rs = exp2f(m - mn);
        float p[4][4]; float ps = 0.f;
#pragma unroll
        for (int j = 0; j < 4; ++j)
#pragma unroll
            for (int r = 0; r < 4; ++r){
                p[j][r] = exp2f(s4[j][r] - mn);
                ps += p[j][r];
            }
        ps += __shfl_xor(ps, 16);
        ps += __shfl_xor(ps, 32);
        l = l * rs + ps; m = mn;
#pragma unroll
        for (int mt = 0; mt < 8; ++mt) acc[mt] *= rs;

        // ---- P -> B-fragment layout, two 32-wide halves ----
        short8 pf0 = redist(pbf2(p[0][0], p[0][1]), pbf2(p[0][2], p[0][3]),
                            pbf2(p[1][0], p[1][1]), pbf2(p[1][2], p[1][3]), g, c);
        short8 pf1 = redist(pbf2(p[2][0], p[2][1]), pbf2(p[2][2], p[2][3]),
                            pbf2(p[3][0], p[3][1]), pbf2(p[3][2], p[3][3]), g, c);

        // ---- PV from LDS V ----
#pragma unroll
        for (int kk = 0; kk < 2; ++kk){
            short8 vf[8];
#pragma unroll
            for (int mt = 0; mt < 8; ++mt){
                const int h = mt*16 + c;
                vf[mt] = *(const short8*)(vb + h*128 + ((kk*64 + g*16) ^ ((h & 7) << 4)));
            }
            const short8 pf = kk ? pf1 : pf0;
            __builtin_amdgcn_s_setprio(1);
#pragma unroll
            for (int mt = 0; mt < 8; ++mt)
                acc[mt] = __builtin_amdgcn_mfma_f32_16x16x32_bf16(vf[mt], pf, acc[mt], 0,0,0);
            __builtin_amdgcn_s_setprio(0);
        }

        // ---- write next tile into the other buffer (late, T14) ----
        if (kt < qt){
#pragma unroll
            for (int p2 = 0; p2 < 4; ++p2){
                const int s = p2*256 + tid;
                const int r = s >> 4, cb = (s & 15) * 16;
                *(i32x4*)(lds[cur ^ 1] + r*256 + (cb ^ ((r & 7) << 4))) = kreg[p2];
                const int h = s >> 3, tb = (s & 7) * 16;
                *(i32x4*)(lds[cur ^ 1] + 16384 + h*128 + (tb ^ ((h & 7) << 4))) = vreg[p2];
            }
        }
    }

    // ---- epilogue: direct normalized store ----
    const float inv = 1.0f / l;
    float* orow = out + ((size_t)b*DT + q) * DH;
#pragma unroll
    for (int mt = 0; mt < 8; ++mt){
        f32x4 v = acc[mt] * inv;
        *(f32x4*)(orow + mt*16 + 4*g) = v;
    }
}

extern "C" void kernel_launch(void* const* d_in, const int* in_sizes, int n_in,
                              void* d_out, int out_size, void* d_ws, size_t ws_size,
                              hipStream_t stream){
    const float* x  = (const float*)d_in[0];
    const float* Wq = (const float*)d_in[1];
    const float* Wk = (const float*)d_in[2];
    const float* Wv = (const float*)d_in[3];
    float* out = (float*)d_out;

    unsigned short* WTc = (unsigned short*)d_ws;         // [32][4][384][8] bf16
    unsigned short* Qb = WTc + 3 * DH * DC;              // [B*T][H]
    unsigned short* Kb = Qb + (size_t)DB * DT * DH;      // [B*T][H]
    unsigned short* VT = Kb + (size_t)DB * DT * DH;      // [B][H][T]

    hipLaunchKernelGGL(prep_wt_kernel, dim3(1536), dim3(256), 0, stream, Wq, Wk, Wv, WTc);
    hipLaunchKernelGGL(qkv_kernel, dim3(256), dim3(512), 0, stream, x, WTc, Qb, Kb, VT);
    hipLaunchKernelGGL(attn_kernel, dim3(DB * (DT / 64)), dim3(256), 0, stream, Qb, Kb, VT, out);
}